// Round 20
// baseline (8329.692 us; speedup 1.0000x reference)
//
#include <hip/hip_runtime.h>

#define TT 512
#define BB 64
#define II 1024
#define HH 1024
#define GG 4096   /* 4*H */
#define BH 65536  /* B*H */
#define NBLK 128

typedef __attribute__((ext_vector_type(8))) short bf16x8;
typedef __attribute__((ext_vector_type(4))) float f32x4;
typedef __attribute__((ext_vector_type(4))) unsigned u32x4;

__device__ __forceinline__ float bf2f(unsigned short u) {
  union { unsigned int i; float f; } v; v.i = ((unsigned int)u) << 16; return v.f;
}
__device__ __forceinline__ unsigned short f2bf(float f) {
  union { float f; unsigned int i; } v; v.f = f;
  return (unsigned short)((v.i + 0x7FFFu + ((v.i >> 16) & 1u)) >> 16);
}
__device__ __forceinline__ bf16x8 pack8(float4 a, float4 b) {
  union { bf16x8 v; unsigned short u[8]; } p;
  p.u[0] = f2bf(a.x); p.u[1] = f2bf(a.y); p.u[2] = f2bf(a.z); p.u[3] = f2bf(a.w);
  p.u[4] = f2bf(b.x); p.u[5] = f2bf(b.y); p.u[6] = f2bf(b.z); p.u[7] = f2bf(b.w);
  return p.v;
}
__device__ __forceinline__ bf16x8 pack8v(f32x4 a, f32x4 b) {
  union { bf16x8 v; unsigned short u[8]; } p;
  p.u[0] = f2bf(a[0]); p.u[1] = f2bf(a[1]); p.u[2] = f2bf(a[2]); p.u[3] = f2bf(a[3]);
  p.u[4] = f2bf(b[0]); p.u[5] = f2bf(b[1]); p.u[6] = f2bf(b[2]); p.u[7] = f2bf(b[3]);
  return p.v;
}
__device__ __forceinline__ float sigmoid_f(float x) { return 1.0f / (1.0f + __expf(-x)); }
__device__ __forceinline__ float tanh_f(float x) {
  float e = __expf(-2.0f * fabsf(x));
  float t = (1.0f - e) / (1.0f + e);
  return copysignf(t, x);
}

__device__ __forceinline__ void st32_uc(unsigned* p, unsigned v) {
  __hip_atomic_store(p, v, __ATOMIC_RELAXED, __HIP_MEMORY_SCOPE_AGENT);
}
__device__ __forceinline__ unsigned ld32_uc(const unsigned* p) {
  return __hip_atomic_load(p, __ATOMIC_RELAXED, __HIP_MEMORY_SCOPE_AGENT);
}
__device__ __forceinline__ void st128_uc(void* p, u32x4 v) {
  asm volatile("global_store_dwordx4 %0, %1, off sc0 sc1" :: "v"(p), "v"(v) : "memory");
}
// LDS monotonic counters (add/store from ONE lane per wave)
__device__ __forceinline__ void lds_add_rel(int* p) {
  __hip_atomic_fetch_add(p, 1, __ATOMIC_RELEASE, __HIP_MEMORY_SCOPE_WORKGROUP);
}
__device__ __forceinline__ int lds_ld_acq(const int* p) {
  return __hip_atomic_load(p, __ATOMIC_ACQUIRE, __HIP_MEMORY_SCOPE_WORKGROUP);
}
__device__ __forceinline__ void lds_st_rel(int* p, int v) {
  __hip_atomic_store(p, v, __ATOMIC_RELEASE, __HIP_MEMORY_SCOPE_WORKGROUP);
}

// ---- fused recurrence over [t0, t0+tc): R13 structure, single-dispatch, no xbf ----
// 128 WGs x 576 threads. Waves 0-3: recurrence; h-GEMM consumed in 8 K-chunks of 128
// (chunk g <-> producer blocks 16g..16g+15), gated by g_prog = 8*s + ng (monotonic).
// Waves 4-7: gx engine reading f32 x DIRECTLY (NT loads, in-register bf16 pack) into
// the 4-slot Dgx ring. Wave 8 on block 0: ballot-aggregator.
__global__ __launch_bounds__(576) void wdlstm_fused(
    const float* __restrict__ w_hh, const float* __restrict__ hh_mask,
    const float* __restrict__ w_ih,
    const float* __restrict__ b_ih, const float* __restrict__ b_hh,
    const float* __restrict__ x,             // [T][B][I] f32 (read by gx engine)
    float* __restrict__ out, float* __restrict__ c_state,
    unsigned* __restrict__ flags,            // [NBLK] 64B-padded + g_prog at +8192B
    unsigned short* __restrict__ hinit,      // [BH] cross-chunk h carry
    unsigned short* __restrict__ hring,      // [tc][BH] fresh slot per step
    int t0, int tc) {
  __shared__ __align__(16) char Wh[65536];            // [32][1024] bf16, XOR-swizzled
  __shared__ __align__(16) char Wi[65536];            // [32][1024] bf16, XOR-swizzled
  __shared__ float Dlds[64][33];                      // h-part D, rows x 32 cols
  __shared__ __align__(8) unsigned short Dgx[4][32][72];  // gx partials ring, col-major
  __shared__ __align__(16) unsigned Hs[64][4];        // h pack: [b][wv] = cols 2wv,2wv+1
  __shared__ int syncv[8];   // 0:cnt_D 1:cnt_EW 2..5:gx_done[w2]

  const int tid = threadIdx.x;
  const int wv  = tid >> 6, l = tid & 63;
  const int ln  = l & 15, lq = l >> 4;
  const int j0h = blockIdx.x * 8;
  unsigned* g_prog = flags + 2048;                    // +8192 B

  // preload W slices (576-thread stride): LDS row n = weight row (n>>3)*H + j0h + (n&7)
  for (int c = tid; c < 4096; c += 576) {
    int n = c >> 7, cc = c & 127;
    int wrow = (n >> 3) * HH + j0h + (n & 7);
    int addr = (n * 2048 + cc * 16) ^ ((n & 7) << 4);
    {
      const float* sw = w_hh   + (size_t)wrow * HH + cc * 8;
      const float* sm = hh_mask + (size_t)wrow * HH + cc * 8;
      float4 w0 = *(const float4*)sw, w1 = *(const float4*)(sw + 4);
      float4 m0 = *(const float4*)sm, m1 = *(const float4*)(sm + 4);
      float4 p0 = {w0.x * m0.x, w0.y * m0.y, w0.z * m0.z, w0.w * m0.w};
      float4 p1 = {w1.x * m1.x, w1.y * m1.y, w1.z * m1.z, w1.w * m1.w};
      *(bf16x8*)(Wh + addr) = pack8(p0, p1);
    }
    {
      const float* si = w_ih + (size_t)wrow * II + cc * 8;
      float4 a0 = *(const float4*)si, a1 = *(const float4*)(si + 4);
      *(bf16x8*)(Wi + addr) = pack8(a0, a1);
    }
  }
  if (tid < 8) syncv[tid] = 0;
  __syncthreads();   // the ONLY whole-block barrier; roles diverge after this

  if (wv < 4) {
    // ================= recurrence role (tid < 256) =================
    __builtin_amdgcn_s_setprio(1);
    const int b_ew = l;            // elementwise: batch row
    const int jj0  = 2 * wv;       // elementwise: col pair
    float c_reg[2];
    if (t0 == 0) { c_reg[0] = c_reg[1] = 0.f; }
    else {
      float2 cv = *(const float2*)(c_state + (size_t)b_ew * HH + j0h + jj0);
      c_reg[0] = cv.x; c_reg[1] = cv.y;
    }
    float biasv[4][2];
#pragma unroll
    for (int g = 0; g < 4; ++g)
#pragma unroll
      for (int q = 0; q < 2; ++q) {
        int col = g * HH + j0h + jj0 + q;
        biasv[g][q] = b_ih[col] + b_hh[col];
      }
    float* hn_out = out + (size_t)TT * BH;
    float* cn_out = hn_out + BH;

    for (int lt = 0; lt < tc; ++lt) {
      const int t = t0 + lt;
      f32x4 acc[2];
      acc[0] = (f32x4){0.f, 0.f, 0.f, 0.f};
      acc[1] = (f32x4){0.f, 0.f, 0.f, 0.f};

      if (t > 0) {
        const unsigned short* hp = (lt == 0) ? hinit : hring + (size_t)(lt - 1) * BH;
        const unsigned short* ap = hp + (size_t)(16 * wv + ln) * HH + lq * 8;
        int avail = (lt == 0) ? 8 : 0;   // hinit synced by dispatch boundary
        auto ensure = [&](int g) {
          while (avail <= g) {
            int v = (int)ld32_uc(g_prog) - 8 * t;
            if (v > 8) v = 8;
            if (v > avail) avail = v; else __builtin_amdgcn_s_sleep(1);
          }
        };
        bf16x8 a0[4], a1[4];
        ensure(0);
#pragma unroll
        for (int i = 0; i < 4; ++i) a0[i] = *(const bf16x8*)(ap + i * 32);
#pragma unroll
        for (int g = 0; g < 8; ++g) {
          bf16x8* cur = (g & 1) ? a1 : a0;
          bf16x8* nxt = (g & 1) ? a0 : a1;
          if (g < 7) {
            ensure(g + 1);
#pragma unroll
            for (int i = 0; i < 4; ++i)
              nxt[i] = *(const bf16x8*)(ap + (4 * (g + 1) + i) * 32);
          }
#pragma unroll
          for (int i = 0; i < 4; ++i) {
            int kc = 4 * g + i;
#pragma unroll
            for (int ni = 0; ni < 2; ++ni) {
              int n = 16 * ni + ln;
              int baddr = (n * 2048 + kc * 64 + lq * 16) ^ ((n & 7) << 4);
              bf16x8 b = *(const bf16x8*)(Wh + baddr);
              acc[ni] = __builtin_amdgcn_mfma_f32_16x16x32_bf16(cur[i], b, acc[ni], 0, 0, 0);
            }
          }
        }
      }
      // D-fragment -> Dlds: rows 16wv+4lq+r, cols 16ni+ln
#pragma unroll
      for (int ni = 0; ni < 2; ++ni)
#pragma unroll
        for (int r = 0; r < 4; ++r)
          Dlds[16 * wv + 4 * lq + r][16 * ni + ln] = acc[ni][r];
      if (l == 0) lds_add_rel(&syncv[0]);                     // cnt_D: one per wave
      {
        const int tgt = 4 * (lt + 1);
        while (lds_ld_acq(&syncv[0]) < tgt) __builtin_amdgcn_s_sleep(1);
        while (lds_ld_acq(&syncv[2]) < lt + 1 || lds_ld_acq(&syncv[3]) < lt + 1 ||
               lds_ld_acq(&syncv[4]) < lt + 1 || lds_ld_acq(&syncv[5]) < lt + 1)
          __builtin_amdgcn_s_sleep(1);
      }

      // elementwise: 2 states per thread; gate col n = g*8 + jj
      const int slot = lt & 3;
      float hq[2];
#pragma unroll
      for (int q = 0; q < 2; ++q) {
        int jj = jj0 + q;
        float g0 = Dlds[b_ew][ 0 + jj] + bf2f(Dgx[slot][ 0 + jj][b_ew]) + biasv[0][q];
        float g1 = Dlds[b_ew][ 8 + jj] + bf2f(Dgx[slot][ 8 + jj][b_ew]) + biasv[1][q];
        float g2 = Dlds[b_ew][16 + jj] + bf2f(Dgx[slot][16 + jj][b_ew]) + biasv[2][q];
        float g3 = Dlds[b_ew][24 + jj] + bf2f(Dgx[slot][24 + jj][b_ew]) + biasv[3][q];
        float ig = sigmoid_f(g0);
        float fg = sigmoid_f(g1);
        float gg = tanh_f(g2);
        float og = sigmoid_f(g3);
        c_reg[q] = fg * c_reg[q] + ig * gg;
        hq[q] = og * tanh_f(c_reg[q]);
      }
      *(float2*)(out + (size_t)t * BH + (size_t)b_ew * HH + j0h + jj0) = make_float2(hq[0], hq[1]);
      Hs[b_ew][wv] = (unsigned)f2bf(hq[0]) | ((unsigned)f2bf(hq[1]) << 16);
      if (t == TT - 1) {
        *(float2*)(hn_out + (size_t)b_ew * HH + j0h + jj0) = make_float2(hq[0], hq[1]);
        *(float2*)(cn_out + (size_t)b_ew * HH + j0h + jj0) = make_float2(c_reg[0], c_reg[1]);
      }
      if (l == 0) lds_add_rel(&syncv[1]);                     // cnt_EW: one per wave

      if (wv == 0) {
        const int tgt = 4 * (lt + 1);
        while (lds_ld_acq(&syncv[1]) < tgt) __builtin_amdgcn_s_sleep(1);
        u32x4 hv4 = *(const u32x4*)&Hs[l][0];
        char* dst = (char*)hring + ((size_t)lt * BH + (size_t)l * HH + j0h) * 2;
        st128_uc(dst, hv4);
        if (lt == tc - 1)   // cross-chunk carry (dispatch-end flush covers it)
          *(u32x4*)((char*)hinit + ((size_t)l * HH + j0h) * 2) = hv4;
        asm volatile("s_waitcnt vmcnt(0)" ::: "memory");
        if (l == 0) st32_uc(&flags[blockIdx.x * 16], (unsigned)(t + 1));
      }
    }
    *(float2*)(c_state + (size_t)b_ew * HH + j0h + jj0) = make_float2(c_reg[0], c_reg[1]);

  } else if (wv < 8) {
    // ========= gx engine role: reads f32 x directly (NT), packs in-register =========
    const int w2 = wv - 4;
    for (int s = 0; s < tc; ++s) {
      if (s >= 4) {   // slot reuse throttle: elementwise of step s-4 must be done
        const int tgt = 4 * (s - 3);
        while (lds_ld_acq(&syncv[1]) < tgt) __builtin_amdgcn_s_sleep(1);
      }
      f32x4 acc[2];
      acc[0] = (f32x4){0.f, 0.f, 0.f, 0.f};
      acc[1] = (f32x4){0.f, 0.f, 0.f, 0.f};
      const float* ap = x + (size_t)(t0 + s) * BH + (size_t)(16 * w2 + ln) * II + lq * 8;
      bf16x8 aA[8], aB[8];
#pragma unroll
      for (int i = 0; i < 8; ++i) {
        f32x4 u0 = __builtin_nontemporal_load((const f32x4*)(ap + i * 32));
        f32x4 u1 = __builtin_nontemporal_load((const f32x4*)(ap + i * 32 + 4));
        aA[i] = pack8v(u0, u1);
      }
#pragma unroll
      for (int c4 = 0; c4 < 4; ++c4) {
        const bf16x8* cur = (c4 & 1) ? aB : aA;
        bf16x8*       nxt = (c4 & 1) ? aA : aB;
        if (c4 < 3) {
#pragma unroll
          for (int i = 0; i < 8; ++i) {
            f32x4 u0 = __builtin_nontemporal_load((const f32x4*)(ap + (c4 + 1) * 256 + i * 32));
            f32x4 u1 = __builtin_nontemporal_load((const f32x4*)(ap + (c4 + 1) * 256 + i * 32 + 4));
            nxt[i] = pack8v(u0, u1);
          }
        }
#pragma unroll
        for (int i = 0; i < 8; ++i) {
          int kc = c4 * 8 + i;
#pragma unroll
          for (int ni = 0; ni < 2; ++ni) {
            int n = 16 * ni + ln;
            int baddr = (n * 2048 + kc * 64 + lq * 16) ^ ((n & 7) << 4);
            bf16x8 b = *(const bf16x8*)(Wi + baddr);
            acc[ni] = __builtin_amdgcn_mfma_f32_16x16x32_bf16(cur[i], b, acc[ni], 0, 0, 0);
          }
        }
      }
      const int slot = s & 3;
#pragma unroll
      for (int ni = 0; ni < 2; ++ni) {
        unsigned short p[4] = {f2bf(acc[ni][0]), f2bf(acc[ni][1]),
                               f2bf(acc[ni][2]), f2bf(acc[ni][3])};
        *(unsigned long long*)&Dgx[slot][16 * ni + ln][16 * w2 + 4 * lq] =
            *(unsigned long long*)p;
      }
      if (l == 0) lds_st_rel(&syncv[2 + w2], s + 1);   // gx_done[w2]: one per wave
    }

  } else if (blockIdx.x == 0) {
    // ============ ballot-aggregator role (block 0, wave 8) ============
    const unsigned* f0 = flags + (2 * l) * 16;
    const unsigned* f1 = flags + (2 * l + 1) * 16;
    for (int s = t0 + 1; s < t0 + tc; ++s) {
      int pub = 0;
      while (pub < 8) {
        bool mine = ((int)ld32_uc(f0) >= s) && ((int)ld32_uc(f1) >= s);
        unsigned long long b = __ballot(mine);
        int ng = 0;
        while (ng < 8 && ((b >> (8 * ng)) & 0xFFull) == 0xFFull) ++ng;
        if (ng > pub) {
          pub = ng;
          if (l == 0) st32_uc(g_prog, (unsigned)(8 * s + ng));
        } else {
          __builtin_amdgcn_s_sleep(1);
        }
      }
    }
  }
}

extern "C" void kernel_launch(void* const* d_in, const int* in_sizes, int n_in,
                              void* d_out, int out_size, void* d_ws, size_t ws_size,
                              hipStream_t stream) {
  const float* x       = (const float*)d_in[0];
  const float* w_ih    = (const float*)d_in[1];
  const float* w_hh    = (const float*)d_in[2];
  const float* b_ih    = (const float*)d_in[3];
  const float* b_hh    = (const float*)d_in[4];
  const float* hh_mask = (const float*)d_in[5];
  float* out           = (float*)d_out;

  char* ws = (char*)d_ws;
  float* c_state        = (float*)ws;                           // 262144 B
  unsigned* flags       = (unsigned*)(ws + 262144);             // 16384 B (128x64B + g_prog)
  unsigned short* hinit = (unsigned short*)(ws + 278528);       // 131072 B
  unsigned short* hring = (unsigned short*)(ws + 409600);       // TC x 131072 B

  // per step: only the hring slot (128 KB). Cap TC at full TT -> single dispatch.
  const long long fixed = 409600;
  const long long per_t = 131072;
  long long avail = (long long)ws_size - fixed;
  int TC = (int)(avail / per_t);
  if (TC > TT) TC = TT;
  if (TC < 2) TC = 2;

  // flags + g_prog monotonic; reset once per launch (graph-replay-safe)
  (void)hipMemsetAsync(flags, 0, 16384, stream);

  for (int t0 = 0; t0 < TT; t0 += TC) {
    int tc = TT - t0 < TC ? TT - t0 : TC;
    wdlstm_fused<<<NBLK, 576, 0, stream>>>(w_hh, hh_mask, w_ih, b_ih, b_hh, x,
                                           out, c_state, flags, hinit, hring, t0, tc);
  }
}

// Round 21
// 4448.930 us; speedup vs baseline: 1.8723x; 1.8723x over previous
//
#include <hip/hip_runtime.h>

#define TT 512
#define BB 64
#define II 1024
#define HH 1024
#define GG 4096   /* 4*H */
#define BH 65536  /* B*H */
#define NBLK 128

typedef __attribute__((ext_vector_type(8))) short bf16x8;
typedef __attribute__((ext_vector_type(4))) float f32x4;
typedef __attribute__((ext_vector_type(4))) unsigned u32x4;

__device__ __forceinline__ float bf2f(unsigned short u) {
  union { unsigned int i; float f; } v; v.i = ((unsigned int)u) << 16; return v.f;
}
__device__ __forceinline__ unsigned short f2bf(float f) {
  union { float f; unsigned int i; } v; v.f = f;
  return (unsigned short)((v.i + 0x7FFFu + ((v.i >> 16) & 1u)) >> 16);
}
__device__ __forceinline__ bf16x8 pack8(float4 a, float4 b) {
  union { bf16x8 v; unsigned short u[8]; } p;
  p.u[0] = f2bf(a.x); p.u[1] = f2bf(a.y); p.u[2] = f2bf(a.z); p.u[3] = f2bf(a.w);
  p.u[4] = f2bf(b.x); p.u[5] = f2bf(b.y); p.u[6] = f2bf(b.z); p.u[7] = f2bf(b.w);
  return p.v;
}
__device__ __forceinline__ float sigmoid_f(float x) { return 1.0f / (1.0f + __expf(-x)); }
__device__ __forceinline__ float tanh_f(float x) {
  float e = __expf(-2.0f * fabsf(x));
  float t = (1.0f - e) / (1.0f + e);
  return copysignf(t, x);
}

__device__ __forceinline__ void st32_uc(unsigned* p, unsigned v) {
  __hip_atomic_store(p, v, __ATOMIC_RELAXED, __HIP_MEMORY_SCOPE_AGENT);
}
__device__ __forceinline__ unsigned ld32_uc(const unsigned* p) {
  return __hip_atomic_load(p, __ATOMIC_RELAXED, __HIP_MEMORY_SCOPE_AGENT);
}
__device__ __forceinline__ void st128_uc(void* p, u32x4 v) {
  asm volatile("global_store_dwordx4 %0, %1, off sc0 sc1" :: "v"(p), "v"(v) : "memory");
}
// LDS monotonic counters (add/store from ONE lane per wave)
__device__ __forceinline__ void lds_add_rel(int* p) {
  __hip_atomic_fetch_add(p, 1, __ATOMIC_RELEASE, __HIP_MEMORY_SCOPE_WORKGROUP);
}
__device__ __forceinline__ int lds_ld_acq(const int* p) {
  return __hip_atomic_load(p, __ATOMIC_ACQUIRE, __HIP_MEMORY_SCOPE_WORKGROUP);
}
__device__ __forceinline__ void lds_st_rel(int* p, int v) {
  __hip_atomic_store(p, v, __ATOMIC_RELEASE, __HIP_MEMORY_SCOPE_WORKGROUP);
}

// ---------------- x f32 -> bf16 conversion (cached writes; xbf is shared-read) ------
__global__ __launch_bounds__(256) void wdlstm_xconv(
    const float* __restrict__ xc, unsigned short* __restrict__ xbf, int n4) {
  int stride = gridDim.x * blockDim.x;
  for (int i = blockIdx.x * blockDim.x + threadIdx.x; i < n4; i += stride) {
    float4 v = *(const float4*)(xc + (size_t)i * 4);
    unsigned short o[4] = {f2bf(v.x), f2bf(v.y), f2bf(v.z), f2bf(v.w)};
    *(unsigned long long*)(xbf + (size_t)i * 4) = *(unsigned long long*)o;
  }
}

// ---- fused, wave-specialized, K-sliced recurrence over [t0, t0+tc) (R13, 1-shot) ----
// 128 WGs x 576 threads. Waves 0-3: recurrence; h-GEMM consumed in 8 K-chunks of 128
// (chunk g <-> producer blocks 16g..16g+15), gated by g_prog = 8*s + ng (monotonic).
// Waves 4-7: gx engine into 4-slot Dgx ring (cached xbf reads -> L2-shared per XCD).
// Wave 8 on block 0: ballot-aggregator.
__global__ __launch_bounds__(576) void wdlstm_fused(
    const float* __restrict__ w_hh, const float* __restrict__ hh_mask,
    const float* __restrict__ w_ih,
    const float* __restrict__ b_ih, const float* __restrict__ b_hh,
    const unsigned short* __restrict__ xbf,  // [tc][B][I] bf16
    float* __restrict__ out, float* __restrict__ c_state,
    unsigned* __restrict__ flags,            // [NBLK] 64B-padded + g_prog at +8192B
    unsigned short* __restrict__ hinit,      // [BH] cross-chunk h carry
    unsigned short* __restrict__ hring,      // [tc][BH] fresh slot per step
    int t0, int tc) {
  __shared__ __align__(16) char Wh[65536];            // [32][1024] bf16, XOR-swizzled
  __shared__ __align__(16) char Wi[65536];            // [32][1024] bf16, XOR-swizzled
  __shared__ float Dlds[64][33];                      // h-part D, rows x 32 cols
  __shared__ __align__(8) unsigned short Dgx[4][32][72];  // gx ring, col-major
  __shared__ __align__(16) unsigned Hs[64][4];        // h pack: [b][wv] = cols 2wv,2wv+1
  __shared__ int syncv[8];   // 0:cnt_D 1:cnt_EW 2..5:gx_done[w2]

  const int tid = threadIdx.x;
  const int wv  = tid >> 6, l = tid & 63;
  const int ln  = l & 15, lq = l >> 4;
  const int j0h = blockIdx.x * 8;
  unsigned* g_prog = flags + 2048;                    // +8192 B

  // preload W slices (576-thread stride): LDS row n = weight row (n>>3)*H + j0h + (n&7)
  for (int c = tid; c < 4096; c += 576) {
    int n = c >> 7, cc = c & 127;
    int wrow = (n >> 3) * HH + j0h + (n & 7);
    int addr = (n * 2048 + cc * 16) ^ ((n & 7) << 4);
    {
      const float* sw = w_hh   + (size_t)wrow * HH + cc * 8;
      const float* sm = hh_mask + (size_t)wrow * HH + cc * 8;
      float4 w0 = *(const float4*)sw, w1 = *(const float4*)(sw + 4);
      float4 m0 = *(const float4*)sm, m1 = *(const float4*)(sm + 4);
      float4 p0 = {w0.x * m0.x, w0.y * m0.y, w0.z * m0.z, w0.w * m0.w};
      float4 p1 = {w1.x * m1.x, w1.y * m1.y, w1.z * m1.z, w1.w * m1.w};
      *(bf16x8*)(Wh + addr) = pack8(p0, p1);
    }
    {
      const float* si = w_ih + (size_t)wrow * II + cc * 8;
      float4 a0 = *(const float4*)si, a1 = *(const float4*)(si + 4);
      *(bf16x8*)(Wi + addr) = pack8(a0, a1);
    }
  }
  if (tid < 8) syncv[tid] = 0;
  __syncthreads();   // the ONLY whole-block barrier; roles diverge after this

  if (wv < 4) {
    // ================= recurrence role (tid < 256) =================
    __builtin_amdgcn_s_setprio(1);
    const int b_ew = l;            // elementwise: batch row
    const int jj0  = 2 * wv;       // elementwise: col pair
    float c_reg[2];
    if (t0 == 0) { c_reg[0] = c_reg[1] = 0.f; }
    else {
      float2 cv = *(const float2*)(c_state + (size_t)b_ew * HH + j0h + jj0);
      c_reg[0] = cv.x; c_reg[1] = cv.y;
    }
    float biasv[4][2];
#pragma unroll
    for (int g = 0; g < 4; ++g)
#pragma unroll
      for (int q = 0; q < 2; ++q) {
        int col = g * HH + j0h + jj0 + q;
        biasv[g][q] = b_ih[col] + b_hh[col];
      }
    float* hn_out = out + (size_t)TT * BH;
    float* cn_out = hn_out + BH;

    for (int lt = 0; lt < tc; ++lt) {
      const int t = t0 + lt;
      f32x4 acc[2];
      acc[0] = (f32x4){0.f, 0.f, 0.f, 0.f};
      acc[1] = (f32x4){0.f, 0.f, 0.f, 0.f};

      if (t > 0) {
        const unsigned short* hp = (lt == 0) ? hinit : hring + (size_t)(lt - 1) * BH;
        const unsigned short* ap = hp + (size_t)(16 * wv + ln) * HH + lq * 8;
        int avail = (lt == 0) ? 8 : 0;   // hinit synced by dispatch boundary
        auto ensure = [&](int g) {
          while (avail <= g) {
            int v = (int)ld32_uc(g_prog) - 8 * t;
            if (v > 8) v = 8;
            if (v > avail) avail = v; else __builtin_amdgcn_s_sleep(1);
          }
        };
        bf16x8 a0[4], a1[4];
        ensure(0);
#pragma unroll
        for (int i = 0; i < 4; ++i) a0[i] = *(const bf16x8*)(ap + i * 32);
#pragma unroll
        for (int g = 0; g < 8; ++g) {
          bf16x8* cur = (g & 1) ? a1 : a0;
          bf16x8* nxt = (g & 1) ? a0 : a1;
          if (g < 7) {
            ensure(g + 1);
#pragma unroll
            for (int i = 0; i < 4; ++i)
              nxt[i] = *(const bf16x8*)(ap + (4 * (g + 1) + i) * 32);
          }
#pragma unroll
          for (int i = 0; i < 4; ++i) {
            int kc = 4 * g + i;
#pragma unroll
            for (int ni = 0; ni < 2; ++ni) {
              int n = 16 * ni + ln;
              int baddr = (n * 2048 + kc * 64 + lq * 16) ^ ((n & 7) << 4);
              bf16x8 b = *(const bf16x8*)(Wh + baddr);
              acc[ni] = __builtin_amdgcn_mfma_f32_16x16x32_bf16(cur[i], b, acc[ni], 0, 0, 0);
            }
          }
        }
      }
      // D-fragment -> Dlds: rows 16wv+4lq+r, cols 16ni+ln
#pragma unroll
      for (int ni = 0; ni < 2; ++ni)
#pragma unroll
        for (int r = 0; r < 4; ++r)
          Dlds[16 * wv + 4 * lq + r][16 * ni + ln] = acc[ni][r];
      if (l == 0) lds_add_rel(&syncv[0]);                     // cnt_D: one per wave
      {
        const int tgt = 4 * (lt + 1);
        while (lds_ld_acq(&syncv[0]) < tgt) __builtin_amdgcn_s_sleep(1);
        while (lds_ld_acq(&syncv[2]) < lt + 1 || lds_ld_acq(&syncv[3]) < lt + 1 ||
               lds_ld_acq(&syncv[4]) < lt + 1 || lds_ld_acq(&syncv[5]) < lt + 1)
          __builtin_amdgcn_s_sleep(1);
      }

      // elementwise: 2 states per thread; gate col n = g*8 + jj
      const int slot = lt & 3;
      float hq[2];
#pragma unroll
      for (int q = 0; q < 2; ++q) {
        int jj = jj0 + q;
        float g0 = Dlds[b_ew][ 0 + jj] + bf2f(Dgx[slot][ 0 + jj][b_ew]) + biasv[0][q];
        float g1 = Dlds[b_ew][ 8 + jj] + bf2f(Dgx[slot][ 8 + jj][b_ew]) + biasv[1][q];
        float g2 = Dlds[b_ew][16 + jj] + bf2f(Dgx[slot][16 + jj][b_ew]) + biasv[2][q];
        float g3 = Dlds[b_ew][24 + jj] + bf2f(Dgx[slot][24 + jj][b_ew]) + biasv[3][q];
        float ig = sigmoid_f(g0);
        float fg = sigmoid_f(g1);
        float gg = tanh_f(g2);
        float og = sigmoid_f(g3);
        c_reg[q] = fg * c_reg[q] + ig * gg;
        hq[q] = og * tanh_f(c_reg[q]);
      }
      *(float2*)(out + (size_t)t * BH + (size_t)b_ew * HH + j0h + jj0) = make_float2(hq[0], hq[1]);
      Hs[b_ew][wv] = (unsigned)f2bf(hq[0]) | ((unsigned)f2bf(hq[1]) << 16);
      if (t == TT - 1) {
        *(float2*)(hn_out + (size_t)b_ew * HH + j0h + jj0) = make_float2(hq[0], hq[1]);
        *(float2*)(cn_out + (size_t)b_ew * HH + j0h + jj0) = make_float2(c_reg[0], c_reg[1]);
      }
      if (l == 0) lds_add_rel(&syncv[1]);                     // cnt_EW: one per wave

      if (wv == 0) {
        const int tgt = 4 * (lt + 1);
        while (lds_ld_acq(&syncv[1]) < tgt) __builtin_amdgcn_s_sleep(1);
        u32x4 hv4 = *(const u32x4*)&Hs[l][0];
        char* dst = (char*)hring + ((size_t)lt * BH + (size_t)l * HH + j0h) * 2;
        st128_uc(dst, hv4);
        if (lt == tc - 1)   // cross-chunk carry (dispatch-end flush covers it)
          *(u32x4*)((char*)hinit + ((size_t)l * HH + j0h) * 2) = hv4;
        asm volatile("s_waitcnt vmcnt(0)" ::: "memory");
        if (l == 0) st32_uc(&flags[blockIdx.x * 16], (unsigned)(t + 1));
      }
    }
    *(float2*)(c_state + (size_t)b_ew * HH + j0h + jj0) = make_float2(c_reg[0], c_reg[1]);

  } else if (wv < 8) {
    // ================= gx engine role (cached xbf reads) =================
    const int w2 = wv - 4;
    for (int s = 0; s < tc; ++s) {
      if (s >= 4) {   // slot reuse throttle: elementwise of step s-4 must be done
        const int tgt = 4 * (s - 3);
        while (lds_ld_acq(&syncv[1]) < tgt) __builtin_amdgcn_s_sleep(1);
      }
      f32x4 acc[2];
      acc[0] = (f32x4){0.f, 0.f, 0.f, 0.f};
      acc[1] = (f32x4){0.f, 0.f, 0.f, 0.f};
      const unsigned short* ap = xbf + (size_t)s * BH + (size_t)(16 * w2 + ln) * II + lq * 8;
      bf16x8 aA[8], aB[8];
#pragma unroll
      for (int i = 0; i < 8; ++i) aA[i] = *(const bf16x8*)(ap + i * 32);
#pragma unroll
      for (int c4 = 0; c4 < 4; ++c4) {
        const bf16x8* cur = (c4 & 1) ? aB : aA;
        bf16x8*       nxt = (c4 & 1) ? aA : aB;
        if (c4 < 3) {
#pragma unroll
          for (int i = 0; i < 8; ++i) nxt[i] = *(const bf16x8*)(ap + (c4 + 1) * 256 + i * 32);
        }
#pragma unroll
        for (int i = 0; i < 8; ++i) {
          int kc = c4 * 8 + i;
#pragma unroll
          for (int ni = 0; ni < 2; ++ni) {
            int n = 16 * ni + ln;
            int baddr = (n * 2048 + kc * 64 + lq * 16) ^ ((n & 7) << 4);
            bf16x8 b = *(const bf16x8*)(Wi + baddr);
            acc[ni] = __builtin_amdgcn_mfma_f32_16x16x32_bf16(cur[i], b, acc[ni], 0, 0, 0);
          }
        }
      }
      const int slot = s & 3;
#pragma unroll
      for (int ni = 0; ni < 2; ++ni) {
        unsigned short p[4] = {f2bf(acc[ni][0]), f2bf(acc[ni][1]),
                               f2bf(acc[ni][2]), f2bf(acc[ni][3])};
        *(unsigned long long*)&Dgx[slot][16 * ni + ln][16 * w2 + 4 * lq] =
            *(unsigned long long*)p;
      }
      if (l == 0) lds_st_rel(&syncv[2 + w2], s + 1);   // gx_done[w2]: one per wave
    }

  } else if (blockIdx.x == 0) {
    // ============ ballot-aggregator role (block 0, wave 8) ============
    const unsigned* f0 = flags + (2 * l) * 16;
    const unsigned* f1 = flags + (2 * l + 1) * 16;
    for (int s = t0 + 1; s < t0 + tc; ++s) {
      int pub = 0;
      while (pub < 8) {
        bool mine = ((int)ld32_uc(f0) >= s) && ((int)ld32_uc(f1) >= s);
        unsigned long long b = __ballot(mine);
        int ng = 0;
        while (ng < 8 && ((b >> (8 * ng)) & 0xFFull) == 0xFFull) ++ng;
        if (ng > pub) {
          pub = ng;
          if (l == 0) st32_uc(g_prog, (unsigned)(8 * s + ng));
        } else {
          __builtin_amdgcn_s_sleep(1);
        }
      }
    }
  }
}

extern "C" void kernel_launch(void* const* d_in, const int* in_sizes, int n_in,
                              void* d_out, int out_size, void* d_ws, size_t ws_size,
                              hipStream_t stream) {
  const float* x       = (const float*)d_in[0];
  const float* w_ih    = (const float*)d_in[1];
  const float* w_hh    = (const float*)d_in[2];
  const float* b_ih    = (const float*)d_in[3];
  const float* b_hh    = (const float*)d_in[4];
  const float* hh_mask = (const float*)d_in[5];
  float* out           = (float*)d_out;

  char* ws = (char*)d_ws;
  float* c_state        = (float*)ws;                           // 262144 B
  unsigned* flags       = (unsigned*)(ws + 262144);             // 16384 B (128x64B + g_prog)
  unsigned short* hinit = (unsigned short*)(ws + 278528);       // 131072 B
  unsigned short* hring = (unsigned short*)(ws + 409600);       // TC x 131072 B
  // xbf placed after hring (TC-dependent)

  // per step: 128KB (hring) + 128KB (xbf). Cap TC at full TT -> single dispatch
  // when ws permits (ws >= ~129 MB, confirmed by R15/R20 single-dispatch runs).
  const long long fixed = 409600;
  const long long per_t = 131072 + 131072;
  long long avail = (long long)ws_size - fixed;
  int TC = (int)(avail / per_t);
  if (TC > TT) TC = TT;
  if (TC < 2) TC = 2;
  unsigned short* xbf = (unsigned short*)(ws + 409600 + (size_t)TC * 131072);

  // flags + g_prog monotonic; reset once per launch (graph-replay-safe)
  (void)hipMemsetAsync(flags, 0, 16384, stream);

  for (int t0 = 0; t0 < TT; t0 += TC) {
    int tc = TT - t0 < TC ? TT - t0 : TC;
    const float* xc = x + (size_t)t0 * BB * II;
    wdlstm_xconv<<<1024, 256, 0, stream>>>(xc, xbf, tc * BH / 4);
    wdlstm_fused<<<NBLK, 576, 0, stream>>>(w_hh, hh_mask, w_ih, b_ih, b_hh, xbf,
                                           out, c_state, flags, hinit, hring, t0, tc);
  }
}